// Round 2
// baseline (427.321 us; speedup 1.0000x reference)
//
#include <hip/hip_runtime.h>

// B=8, N=2048, C=512. Flash attention + fp16 MFMA pipeline (fp16 chosen over
// bf16 for 4x smaller operand quantization error; all values well in fp16 range).
// ws layout: xb(16MB) h(16MB) l(16MB) gT(16MB) y(16MB) Wt(2MB)  [fp16 bits in short]

typedef __attribute__((ext_vector_type(4))) float f32x4;
typedef __attribute__((ext_vector_type(8))) short s16x8;      // fp16 bit-patterns
typedef __attribute__((ext_vector_type(8))) _Float16 f16x8;   // MFMA operand

__device__ __forceinline__ short f2h(float f) {
  _Float16 h = (_Float16)f;  // v_cvt_f16_f32, RTN
  return __builtin_bit_cast(short, h);
}

#define MFMA(a, b, c) __builtin_amdgcn_mfma_f32_16x16x32_f16(a, b, c, 0, 0, 0)

// ---------------- conversion kernels ----------------

__global__ __launch_bounds__(256) void conv_x_kernel(const float* __restrict__ x,
                                                     short* __restrict__ xb) {
  int i = blockIdx.x * 256 + threadIdx.x;  // 1,048,576 chunks of 8 elements
  const float4* xv = (const float4*)x;
  float4 a = xv[2 * i], b = xv[2 * i + 1];
  s16x8 o;
  o[0] = f2h(a.x); o[1] = f2h(a.y); o[2] = f2h(a.z); o[3] = f2h(a.w);
  o[4] = f2h(b.x); o[5] = f2h(b.y); o[6] = f2h(b.z); o[7] = f2h(b.w);
  ((s16x8*)xb)[i] = o;
}

// Wt[w][n][k] = W_w[k][n]  (fp16). Coalesced writes, L2-cached strided reads.
__global__ __launch_bounds__(256) void conv_w_kernel(const float* __restrict__ Wh,
                                                     const float* __restrict__ Wl,
                                                     const float* __restrict__ Wg,
                                                     const float* __restrict__ Wm,
                                                     short* __restrict__ Wt) {
  int idx = blockIdx.x * 256 + threadIdx.x;  // 4 * 262144
  int k = idx & 511, n = (idx >> 9) & 511, w = idx >> 18;
  const float* W = (w == 0) ? Wh : (w == 1) ? Wl : (w == 2) ? Wg : Wm;
  Wt[idx] = f2h(W[k * 512 + n]);
}

// ---------------- fused 3-way MLP GEMM ----------------
// z=0 -> h (row-major), z=1 -> l (row-major), z=2 -> g stored transposed gT[b][c][m]

__global__ __launch_bounds__(256) void mlp3_kernel(const short* __restrict__ A,
                                                   const short* __restrict__ Wt_all,
                                                   const float* __restrict__ bh,
                                                   const float* __restrict__ bl,
                                                   const float* __restrict__ bg,
                                                   short* __restrict__ h,
                                                   short* __restrict__ l,
                                                   short* __restrict__ gT) {
  int z = blockIdx.z;
  const short* Wt = Wt_all + z * 262144;
  const float* bias = (z == 0) ? bh : (z == 1) ? bl : bg;

  __shared__ __align__(16) short lds_a[128 * 40];
  __shared__ __align__(16) short lds_b[128 * 40];
  int tid = threadIdx.x, lane = tid & 63, w = tid >> 6;
  int wm = w >> 1, wn = w & 1;
  int bm = blockIdx.x * 128, bn = blockIdx.y * 128;

  f32x4 acc[4][4];
#pragma unroll
  for (int mi = 0; mi < 4; ++mi)
#pragma unroll
    for (int ni = 0; ni < 4; ++ni) acc[mi][ni] = (f32x4){0.f, 0.f, 0.f, 0.f};

  for (int k0 = 0; k0 < 512; k0 += 32) {
#pragma unroll
    for (int it = 0; it < 2; ++it) {
      int chunk = tid + it * 256;  // 512 chunks: 128 rows x 4 chunks of 8
      int row = chunk >> 2, c8 = (chunk & 3) * 8;
      *(s16x8*)&lds_a[row * 40 + c8] =
          *(const s16x8*)&A[(size_t)(bm + row) * 512 + k0 + c8];
      *(s16x8*)&lds_b[row * 40 + c8] =
          *(const s16x8*)&Wt[(bn + row) * 512 + k0 + c8];
    }
    __syncthreads();
    f16x8 af[4], bfr[4];
#pragma unroll
    for (int mi = 0; mi < 4; ++mi)
      af[mi] = *(const f16x8*)&lds_a[(wm * 64 + mi * 16 + (lane & 15)) * 40 +
                                     (lane >> 4) * 8];
#pragma unroll
    for (int ni = 0; ni < 4; ++ni)
      bfr[ni] = *(const f16x8*)&lds_b[(wn * 64 + ni * 16 + (lane & 15)) * 40 +
                                      (lane >> 4) * 8];
#pragma unroll
    for (int mi = 0; mi < 4; ++mi)
#pragma unroll
      for (int ni = 0; ni < 4; ++ni) acc[mi][ni] = MFMA(af[mi], bfr[ni], acc[mi][ni]);
    __syncthreads();
  }

#pragma unroll
  for (int mi = 0; mi < 4; ++mi)
#pragma unroll
    for (int ni = 0; ni < 4; ++ni) {
      int col = bn + wn * 64 + ni * 16 + (lane & 15);
      float bv = bias[col];
#pragma unroll
      for (int r = 0; r < 4; ++r) {
        int row = bm + wm * 64 + mi * 16 + (lane >> 4) * 4 + r;
        float v = fmaxf(acc[mi][ni][r] + bv, 0.0f);
        short o = f2h(v);
        if (z == 0) h[(size_t)row * 512 + col] = o;
        else if (z == 1) l[(size_t)row * 512 + col] = o;
        else {
          int bb = row >> 11, mm = row & 2047;
          gT[((size_t)bb * 512 + col) * 2048 + mm] = o;
        }
      }
    }
}

// ---------------- flash attention + residual ----------------
// block: 4 waves x 16 queries = 64 queries. Key tiles of 32, D=512.

__global__ __launch_bounds__(256, 1) void attn_kernel(const short* __restrict__ lmat,
                                                      const short* __restrict__ hmat,
                                                      const short* __restrict__ gT,
                                                      const float* __restrict__ x,
                                                      short* __restrict__ y) {
  __shared__ __align__(16) short lds_k[32 * 520];   // K tile [32 keys][512], pad 8
  __shared__ __align__(16) short lds_g[256 * 40];   // gT half tile [256 c][32 keys], pad 8
  __shared__ __align__(16) short lds_p[4][16 * 40]; // per-wave P [16 q][32 keys]
  int tid = threadIdx.x, lane = tid & 63, w = tid >> 6;
  int b = blockIdx.y;
  int q0 = blockIdx.x * 64 + w * 16;
  const short* lb = lmat + (size_t)b * 2048 * 512;
  const short* hb = hmat + (size_t)b * 2048 * 512;
  const short* gb = gT + (size_t)b * 512 * 2048;

  // Q fragments resident: 16 k-steps x 8 fp16
  f16x8 qf[16];
  {
    int q = q0 + (lane & 15);
#pragma unroll
    for (int ks = 0; ks < 16; ++ks)
      qf[ks] = *(const f16x8*)&lb[(size_t)q * 512 + ks * 32 + (lane >> 4) * 8];
  }
  f32x4 accO[32];
#pragma unroll
  for (int i = 0; i < 32; ++i) accO[i] = (f32x4){0.f, 0.f, 0.f, 0.f};
  float mrun[4], lsum[4];
#pragma unroll
  for (int r = 0; r < 4; ++r) { mrun[r] = -3e38f; lsum[r] = 0.f; }

  for (int kt = 0; kt < 64; ++kt) {
    int key0 = kt * 32;
    // stage K tile (32x512) and lower G half (rows 0..255 of gT slice)
#pragma unroll
    for (int it = 0; it < 8; ++it) {
      int chunk = tid + it * 256;  // 2048 chunks
      int row = chunk >> 6, c8 = (chunk & 63) * 8;
      *(s16x8*)&lds_k[row * 520 + c8] =
          *(const s16x8*)&hb[(size_t)(key0 + row) * 512 + c8];
    }
#pragma unroll
    for (int it = 0; it < 4; ++it) {
      int chunk = tid + it * 256;  // 1024 chunks
      int row = chunk >> 2, c8 = (chunk & 3) * 8;
      *(s16x8*)&lds_g[row * 40 + c8] =
          *(const s16x8*)&gb[(size_t)row * 2048 + key0 + c8];
    }
    __syncthreads();

    // S = Q K^T  (two 16-key column tiles)
    f32x4 s0 = {0.f, 0.f, 0.f, 0.f}, s1 = {0.f, 0.f, 0.f, 0.f};
#pragma unroll
    for (int ks = 0; ks < 16; ++ks) {
      f16x8 kf = *(const f16x8*)&lds_k[(lane & 15) * 520 + ks * 32 + (lane >> 4) * 8];
      s0 = MFMA(qf[ks], kf, s0);
    }
#pragma unroll
    for (int ks = 0; ks < 16; ++ks) {
      f16x8 kf = *(const f16x8*)&lds_k[(16 + (lane & 15)) * 520 + ks * 32 + (lane >> 4) * 8];
      s1 = MFMA(qf[ks], kf, s1);
    }

    // online softmax (rows live across the 16 lanes of each l>>4 group)
    float scale[4];
#pragma unroll
    for (int r = 0; r < 4; ++r) {
      float mx = fmaxf(s0[r], s1[r]);
#pragma unroll
      for (int m = 1; m < 16; m <<= 1) mx = fmaxf(mx, __shfl_xor(mx, m));
      float mnew = fmaxf(mrun[r], mx);
      float p0 = __expf(s0[r] - mnew);
      float p1 = __expf(s1[r] - mnew);
      int qr = (lane >> 4) * 4 + r;
      lds_p[w][qr * 40 + (lane & 15)] = f2h(p0);
      lds_p[w][qr * 40 + 16 + (lane & 15)] = f2h(p1);
      float rs = p0 + p1;
#pragma unroll
      for (int m = 1; m < 16; m <<= 1) rs += __shfl_xor(rs, m);
      float sc = __expf(mrun[r] - mnew);
      lsum[r] = lsum[r] * sc + rs;
      mrun[r] = mnew;
      scale[r] = sc;
    }
#pragma unroll
    for (int nf = 0; nf < 32; ++nf) {
      accO[nf][0] *= scale[0]; accO[nf][1] *= scale[1];
      accO[nf][2] *= scale[2]; accO[nf][3] *= scale[3];
    }
    __syncthreads();  // P visible; G lower stable

    // PV lower half (d = 0..255)
    f16x8 pa = *(const f16x8*)&lds_p[w][(lane & 15) * 40 + (lane >> 4) * 8];
#pragma unroll
    for (int nf = 0; nf < 16; ++nf) {
      f16x8 gf = *(const f16x8*)&lds_g[(nf * 16 + (lane & 15)) * 40 + (lane >> 4) * 8];
      accO[nf] = MFMA(pa, gf, accO[nf]);
    }
    __syncthreads();

    // stage upper G half (rows 256..511)
#pragma unroll
    for (int it = 0; it < 4; ++it) {
      int chunk = tid + it * 256;
      int row = chunk >> 2, c8 = (chunk & 3) * 8;
      *(s16x8*)&lds_g[row * 40 + c8] =
          *(const s16x8*)&gb[(size_t)(256 + row) * 2048 + key0 + c8];
    }
    __syncthreads();

    // PV upper half (d = 256..511)
#pragma unroll
    for (int nf = 0; nf < 16; ++nf) {
      f16x8 gf = *(const f16x8*)&lds_g[(nf * 16 + (lane & 15)) * 40 + (lane >> 4) * 8];
      accO[16 + nf] = MFMA(pa, gf, accO[16 + nf]);
    }
    __syncthreads();
  }

  // epilogue: divide by softmax denom, add residual x, store fp16 y
#pragma unroll
  for (int nf = 0; nf < 32; ++nf) {
    int c = nf * 16 + (lane & 15);
#pragma unroll
    for (int r = 0; r < 4; ++r) {
      int q = q0 + (lane >> 4) * 4 + r;
      float v = accO[nf][r] / lsum[r];
      v += x[((size_t)b * 2048 + q) * 512 + c];
      y[((size_t)b * 2048 + q) * 512 + c] = f2h(v);
    }
  }
}

// ---------------- final GEMM: relu(y @ Wm + bm) -> f32 out ----------------

__global__ __launch_bounds__(256) void final_gemm_kernel(const short* __restrict__ A,
                                                         const short* __restrict__ Wt,
                                                         const float* __restrict__ bias,
                                                         float* __restrict__ out) {
  __shared__ __align__(16) short lds_a[128 * 40];
  __shared__ __align__(16) short lds_b[128 * 40];
  int tid = threadIdx.x, lane = tid & 63, w = tid >> 6;
  int wm = w >> 1, wn = w & 1;
  int bm = blockIdx.x * 128, bn = blockIdx.y * 128;

  f32x4 acc[4][4];
#pragma unroll
  for (int mi = 0; mi < 4; ++mi)
#pragma unroll
    for (int ni = 0; ni < 4; ++ni) acc[mi][ni] = (f32x4){0.f, 0.f, 0.f, 0.f};

  for (int k0 = 0; k0 < 512; k0 += 32) {
#pragma unroll
    for (int it = 0; it < 2; ++it) {
      int chunk = tid + it * 256;
      int row = chunk >> 2, c8 = (chunk & 3) * 8;
      *(s16x8*)&lds_a[row * 40 + c8] =
          *(const s16x8*)&A[(size_t)(bm + row) * 512 + k0 + c8];
      *(s16x8*)&lds_b[row * 40 + c8] =
          *(const s16x8*)&Wt[(bn + row) * 512 + k0 + c8];
    }
    __syncthreads();
    f16x8 af[4], bfr[4];
#pragma unroll
    for (int mi = 0; mi < 4; ++mi)
      af[mi] = *(const f16x8*)&lds_a[(wm * 64 + mi * 16 + (lane & 15)) * 40 +
                                     (lane >> 4) * 8];
#pragma unroll
    for (int ni = 0; ni < 4; ++ni)
      bfr[ni] = *(const f16x8*)&lds_b[(wn * 64 + ni * 16 + (lane & 15)) * 40 +
                                      (lane >> 4) * 8];
#pragma unroll
    for (int mi = 0; mi < 4; ++mi)
#pragma unroll
      for (int ni = 0; ni < 4; ++ni) acc[mi][ni] = MFMA(af[mi], bfr[ni], acc[mi][ni]);
    __syncthreads();
  }

#pragma unroll
  for (int mi = 0; mi < 4; ++mi)
#pragma unroll
    for (int ni = 0; ni < 4; ++ni) {
      int col = bn + wn * 64 + ni * 16 + (lane & 15);
      float bv = bias[col];
#pragma unroll
      for (int r = 0; r < 4; ++r) {
        int row = bm + wm * 64 + mi * 16 + (lane >> 4) * 4 + r;
        out[(size_t)row * 512 + col] = fmaxf(acc[mi][ni][r] + bv, 0.0f);
      }
    }
}

// ---------------- host launch ----------------

extern "C" void kernel_launch(void* const* d_in, const int* in_sizes, int n_in,
                              void* d_out, int out_size, void* d_ws, size_t ws_size,
                              hipStream_t stream) {
  const float* x  = (const float*)d_in[0];
  const float* Wh = (const float*)d_in[1];
  const float* bh = (const float*)d_in[2];
  const float* Wl = (const float*)d_in[3];
  const float* bl = (const float*)d_in[4];
  const float* Wg = (const float*)d_in[5];
  const float* bg = (const float*)d_in[6];
  const float* Wm = (const float*)d_in[7];
  const float* bm = (const float*)d_in[8];

  char* ws = (char*)d_ws;
  const size_t SZ = 16777216;  // 16 MB per fp16 [16384][512] buffer
  short* xb  = (short*)(ws + 0 * SZ);
  short* h   = (short*)(ws + 1 * SZ);
  short* l   = (short*)(ws + 2 * SZ);
  short* gT  = (short*)(ws + 3 * SZ);
  short* y   = (short*)(ws + 4 * SZ);
  short* Wt  = (short*)(ws + 5 * SZ);  // 4 x [512][512] fp16 = 2 MB

  conv_x_kernel<<<4096, 256, 0, stream>>>(x, xb);
  conv_w_kernel<<<4096, 256, 0, stream>>>(Wh, Wl, Wg, Wm, Wt);
  mlp3_kernel<<<dim3(128, 4, 3), 256, 0, stream>>>(xb, Wt, bh, bl, bg, h, l, gT);
  attn_kernel<<<dim3(32, 8), 256, 0, stream>>>(l, h, gT, x, y);
  final_gemm_kernel<<<dim3(128, 4), 256, 0, stream>>>(y, Wt + 3 * 262144, bm,
                                                      (float*)d_out);
}